// Round 2
// baseline (2335.649 us; speedup 1.0000x reference)
//
#include <hip/hip_runtime.h>
#include <math.h>

#define LN 8      // layers
#define NRBF 256
#define FD 16
#define OUTD 3
#define KC (-0.72134752044f)   // -0.5 * log2(e)

typedef __attribute__((ext_vector_type(8))) short short8;    // 8 x bf16
typedef __attribute__((ext_vector_type(16))) float floatx16;
typedef __attribute__((ext_vector_type(2))) float floatx2;

__device__ __forceinline__ short f2bf(float f) {
    unsigned u = __builtin_bit_cast(unsigned, f);
    u += 0x7fffu + ((u >> 16) & 1u);          // RNE
    return (short)(u >> 16);
}

// 32x32x16 layouts (KC folded into coefficients, t3 folded into W):
//   PKB: short8 entry g = j*1024 + t*128 + s*64 + l   (16 KB per j)
//        lane l: n = t*32 + (l&31), kh = l>>5; elem e: f = s*8 + kh*4 + (e>>1)
//        e even -> KC*A_f ; e odd -> -2*KC*A_f*C_f    (A = exp(beta))
//   EPI: float4 entry (j*8+t)*32 + (n&31) = {W'0, W'1, W'2, 0}
//        W'o = W[o][j*256+n] * exp2(KC * t3prefix_j[n])

__global__ __launch_bounds__(256) void prep(
    const float* __restrict__ centers, const float* __restrict__ betas,
    const float* __restrict__ W, short* __restrict__ PKB, float* __restrict__ EPI)
{
    __shared__ float ls[LN * 32];
    int blk = blockIdx.x;
    int tid = threadIdx.x;
    if (blk < 32) {
        int g  = blk * 256 + tid;          // = j*1024 + t*128 + s*64 + l (linear)
        int l  = g & 63;
        int s  = (g >> 6) & 1;
        int j  = g >> 10;
        int n  = ((g >> 7) & 7) * 32 + (l & 31);
        int kh = l >> 5;
        int f0 = s * 8 + kh * 4;
        size_t base = ((size_t)(j * NRBF + n)) * FD + f0;
        float4 bq = *(const float4*)(betas + base);
        float4 cq = *(const float4*)(centers + base);
        float a0 = KC * __expf(bq.x), a1 = KC * __expf(bq.y);
        float a2 = KC * __expf(bq.z), a3 = KC * __expf(bq.w);
        short8 v;
        v[0] = f2bf(a0); v[1] = f2bf(-2.0f * a0 * cq.x);
        v[2] = f2bf(a1); v[3] = f2bf(-2.0f * a1 * cq.y);
        v[4] = f2bf(a2); v[5] = f2bf(-2.0f * a2 * cq.z);
        v[6] = f2bf(a3); v[7] = f2bf(-2.0f * a3 * cq.w);
        *((short8*)(PKB + (size_t)g * 8)) = v;
    } else {
        int jj = tid >> 5;                  // 0..7
        int nl = tid & 31;
        int n  = (blk - 32) * 32 + nl;
        const float* bp = betas   + ((size_t)(jj * NRBF + n)) * FD;
        const float* cp = centers + ((size_t)(jj * NRBF + n)) * FD;
        float s = 0.f;
#pragma unroll
        for (int q = 0; q < 4; ++q) {
            float4 bq = *(const float4*)(bp + q * 4);
            float4 cq = *(const float4*)(cp + q * 4);
            s = fmaf(__expf(bq.x) * cq.x, cq.x, s);
            s = fmaf(__expf(bq.y) * cq.y, cq.y, s);
            s = fmaf(__expf(bq.z) * cq.z, cq.z, s);
            s = fmaf(__expf(bq.w) * cq.w, cq.w, s);
        }
        ls[jj * 32 + nl] = s;
        __syncthreads();
        float t3 = 0.f;
        for (int j2 = 0; j2 <= jj; ++j2) t3 += ls[j2 * 32 + nl];
        float E = __builtin_amdgcn_exp2f(KC * t3);
        float4 e;
        e.x = W[0 * (LN * NRBF) + jj * NRBF + n] * E;
        e.y = W[1 * (LN * NRBF) + jj * NRBF + n] * E;
        e.z = W[2 * (LN * NRBF) + jj * NRBF + n] * E;
        e.w = 0.f;
        ((float4*)EPI)[(jj * 8 + (n >> 5)) * 32 + (n & 31)] = e;
    }
}

// build an A-fragment: elem e even -> x_f^2, odd -> x_f  (f = e>>1 of the quad)
// NOTE: macro parameter must NOT be named x/y/z/w (member-access capture!)
#define CVT(dst, vv)  do {                                         \
        short8 f_;                                                 \
        f_[0] = f2bf((vv).x * (vv).x); f_[1] = f2bf((vv).x);       \
        f_[2] = f2bf((vv).y * (vv).y); f_[3] = f2bf((vv).y);       \
        f_[4] = f2bf((vv).z * (vv).z); f_[5] = f2bf((vv).z);       \
        f_[6] = f2bf((vv).w * (vv).w); f_[7] = f2bf((vv).w);       \
        (dst) = f_; } while (0)

// One wave owns a 32-sample tile x all 256 n x all 8 layers.
// Per j: 16x mfma_32x32x16 (8 n-tiles x 2 k-steps), then 8 ep-reads + 128 exps.
// acc[t] carries the KC-scaled (term1 - 2*term2) prefix across j; the exp
// argument is acc directly (KC in PKB, t3 in W').
__global__ __launch_bounds__(256, 2) void rbf_mfma(
    const float* __restrict__ feats, const short* __restrict__ PKB,
    const float* __restrict__ EPI, const float* __restrict__ bias,
    float* __restrict__ out, int B)
{
    __shared__ short8 pk_s[2][16 * 64];   // 2 x 16 KB
    __shared__ float4 ep_s[2][8 * 32];    // 2 x 4 KB

    int tid  = threadIdx.x;
    int lane = tid & 63;
    int w    = tid >> 6;
    int ntile = (B + 31) >> 5;
    int tile = blockIdx.x * 4 + w;
    bool tvalid = (tile < ntile);
    if (!tvalid) tile = ntile - 1;        // duplicate work, no store
    int b0  = tile * 32;
    int s32 = lane & 31;                  // sample-in-tile for A, n-in-32 for D
    int kh  = lane >> 5;
    int brow = b0 + s32; if (brow >= B) brow = B - 1;
    const float* xrow = feats + (size_t)brow * (LN * FD) + kh * 4;

#define STAGE(buf, jv)                                                          \
    do {                                                                        \
        _Pragma("unroll")                                                       \
        for (int i = 0; i < 4; ++i) {                                           \
            const short* gp = PKB + ((size_t)(jv) * 1024 + (w * 4 + i) * 64 + lane) * 8; \
            __builtin_amdgcn_global_load_lds(                                   \
                (const __attribute__((address_space(1))) void*)gp,              \
                (__attribute__((address_space(3))) void*)&pk_s[buf][(w * 4 + i) * 64], \
                16, 0, 0);                                                      \
        }                                                                       \
        const float* ge = EPI + ((size_t)(jv) * 256 + w * 64 + lane) * 4;       \
        __builtin_amdgcn_global_load_lds(                                       \
            (const __attribute__((address_space(1))) void*)ge,                  \
            (__attribute__((address_space(3))) void*)&ep_s[buf][w * 64],        \
            16, 0, 0);                                                          \
    } while (0)

    floatx16 acc[8];
#pragma unroll
    for (int t = 0; t < 8; ++t)
#pragma unroll
        for (int q = 0; q < 16; ++q) acc[t][q] = 0.f;

    floatx2 o01[16];
    float   o2[16];
#pragma unroll
    for (int r = 0; r < 16; ++r) { o01[r] = (floatx2){0.f, 0.f}; o2[r] = 0.f; }

    // j = 0 A-fragments (features kh*4.. and 8+kh*4..)
    float4 xa = *(const float4*)(xrow + 0);
    float4 xb = *(const float4*)(xrow + 8);
    short8 af0, af1;
    CVT(af0, xa);
    CVT(af1, xb);

    STAGE(0, 0);
    __syncthreads();

#pragma unroll
    for (int j = 0; j < LN; ++j) {
        int cur = j & 1;
        float4 xna, xnb;
        if (j < LN - 1) {
            STAGE(cur ^ 1, j + 1);
            xna = *(const float4*)(xrow + (j + 1) * FD);
            xnb = *(const float4*)(xrow + (j + 1) * FD + 8);
        }

        // ---- MFMA phase: 8 independent prefix chains, 2 k-steps each ----
#pragma unroll
        for (int t = 0; t < 8; ++t) {
            short8 bf0 = pk_s[cur][(t * 2 + 0) * 64 + lane];
            short8 bf1 = pk_s[cur][(t * 2 + 1) * 64 + lane];
            acc[t] = __builtin_amdgcn_mfma_f32_32x32x16_bf16(af0, bf0, acc[t], 0, 0, 0);
            acc[t] = __builtin_amdgcn_mfma_f32_32x32x16_bf16(af1, bf1, acc[t], 0, 0, 0);
        }

        // ---- VALU phase: 128 independent exps + projection ----
#pragma unroll
        for (int t = 0; t < 8; ++t) {
            float4 e = ep_s[cur][t * 32 + s32];
            floatx2 exy = {e.x, e.y};
#pragma unroll
            for (int r = 0; r < 16; ++r) {
                float rv = __builtin_amdgcn_exp2f(acc[t][r]);
                o01[r] += (floatx2){rv, rv} * exy;
                o2[r]   = fmaf(rv, e.z, o2[r]);
            }
        }

        if (j < LN - 1) { CVT(af0, xna); CVT(af1, xnb); }
        __syncthreads();
    }
#undef STAGE

    // reduce over the 32 n-lanes (within each lane-half; rows differ by kh)
    float bv = (s32 < OUTD) ? bias[s32] : 0.f;
#pragma unroll
    for (int r = 0; r < 16; ++r) {
        float ax = o01[r].x, ay = o01[r].y, az = o2[r];
        ax += __shfl_xor(ax, 1);  ay += __shfl_xor(ay, 1);  az += __shfl_xor(az, 1);
        ax += __shfl_xor(ax, 2);  ay += __shfl_xor(ay, 2);  az += __shfl_xor(az, 2);
        ax += __shfl_xor(ax, 4);  ay += __shfl_xor(ay, 4);  az += __shfl_xor(az, 4);
        ax += __shfl_xor(ax, 8);  ay += __shfl_xor(ay, 8);  az += __shfl_xor(az, 8);
        ax += __shfl_xor(ax, 16); ay += __shfl_xor(ay, 16); az += __shfl_xor(az, 16);
        if (tvalid && s32 < OUTD) {
            int row = (r & 3) + 8 * (r >> 2) + 4 * kh;   // D-row = sample-in-tile
            int gr  = b0 + row;
            float val = (s32 == 0) ? ax : (s32 == 1) ? ay : az;
            if (gr < B) out[(size_t)gr * OUTD + s32] = val + bv;
        }
    }
}

extern "C" void kernel_launch(void* const* d_in, const int* in_sizes, int n_in,
                              void* d_out, int out_size, void* d_ws, size_t ws_size,
                              hipStream_t stream) {
    // inputs: 0=x (UNUSED by reference), 1=feats, 2=centers, 3=betas, 4=W, 5=b
    const float* feats   = (const float*)d_in[1];
    const float* centers = (const float*)d_in[2];
    const float* betas   = (const float*)d_in[3];
    const float* W       = (const float*)d_in[4];
    const float* bias    = (const float*)d_in[5];
    float* out = (float*)d_out;
    int B = in_sizes[1] / (LN * FD);

    short* PKB = (short*)d_ws;                       // 65536 shorts = 128 KB
    float* EPI = (float*)((char*)d_ws + 65536 * 2);  // 8192 floats = 32 KB

    prep<<<40, 256, 0, stream>>>(centers, betas, W, PKB, EPI);

    int tiles  = (B + 31) / 32;
    int blocks = (tiles + 3) / 4;
    rbf_mfma<<<blocks, 256, 0, stream>>>(feats, PKB, EPI, bias, out, B);
}

// Round 3
// 1412.186 us; speedup vs baseline: 1.6539x; 1.6539x over previous
//
#include <hip/hip_runtime.h>
#include <math.h>

#define LN 8      // layers
#define NRBF 256
#define FD 16
#define OUTD 3
#define KC (-0.72134752044f)   // -0.5 * log2(e)

typedef __attribute__((ext_vector_type(8))) short short8;    // 8 x bf16
typedef __attribute__((ext_vector_type(16))) float floatx16;
typedef __attribute__((ext_vector_type(2))) float floatx2;

__device__ __forceinline__ short f2bf(float f) {
    unsigned u = __builtin_bit_cast(unsigned, f);
    u += 0x7fffu + ((u >> 16) & 1u);          // RNE
    return (short)(u >> 16);
}

// 32x32x16 layouts, t-MAJOR (so one n-tile's full j-chain is contiguous):
//   PKB: short8 entry g = t*1024 + j*128 + s*64 + l   (16 KB per t)
//        lane l: n = t*32 + (l&31), kh = l>>5; elem e: f = s*8 + kh*4 + (e>>1)
//        e even -> KC*A_f ; e odd -> -2*KC*A_f*C_f    (A = exp(beta))
//   EPI: float4 entry (t*8+j)*32 + (n&31) = {W'0, W'1, W'2, 0}   (4 KB per t)
//        W'o = W[o][j*256+n] * exp2(KC * t3prefix_j[n])

__global__ __launch_bounds__(256) void prep(
    const float* __restrict__ centers, const float* __restrict__ betas,
    const float* __restrict__ W, short* __restrict__ PKB, float* __restrict__ EPI)
{
    __shared__ float ls[LN * 32];
    int blk = blockIdx.x;
    int tid = threadIdx.x;
    if (blk < 32) {
        int g  = blk * 256 + tid;          // = t*1024 + j*128 + s*64 + l (linear)
        int l  = g & 63;
        int s  = (g >> 6) & 1;
        int j  = (g >> 7) & 7;
        int t  = g >> 10;
        int n  = t * 32 + (l & 31);
        int kh = l >> 5;
        int f0 = s * 8 + kh * 4;
        size_t base = ((size_t)(j * NRBF + n)) * FD + f0;
        float4 bq = *(const float4*)(betas + base);
        float4 cq = *(const float4*)(centers + base);
        float a0 = KC * __expf(bq.x), a1 = KC * __expf(bq.y);
        float a2 = KC * __expf(bq.z), a3 = KC * __expf(bq.w);
        short8 v;
        v[0] = f2bf(a0); v[1] = f2bf(-2.0f * a0 * cq.x);
        v[2] = f2bf(a1); v[3] = f2bf(-2.0f * a1 * cq.y);
        v[4] = f2bf(a2); v[5] = f2bf(-2.0f * a2 * cq.z);
        v[6] = f2bf(a3); v[7] = f2bf(-2.0f * a3 * cq.w);
        *((short8*)(PKB + (size_t)g * 8)) = v;
    } else {
        int jj = tid >> 5;                  // 0..7
        int nl = tid & 31;
        int n  = (blk - 32) * 32 + nl;
        const float* bp = betas   + ((size_t)(jj * NRBF + n)) * FD;
        const float* cp = centers + ((size_t)(jj * NRBF + n)) * FD;
        float s = 0.f;
#pragma unroll
        for (int q = 0; q < 4; ++q) {
            float4 bq = *(const float4*)(bp + q * 4);
            float4 cq = *(const float4*)(cp + q * 4);
            s = fmaf(__expf(bq.x) * cq.x, cq.x, s);
            s = fmaf(__expf(bq.y) * cq.y, cq.y, s);
            s = fmaf(__expf(bq.z) * cq.z, cq.z, s);
            s = fmaf(__expf(bq.w) * cq.w, cq.w, s);
        }
        ls[jj * 32 + nl] = s;
        __syncthreads();
        float t3 = 0.f;
        for (int j2 = 0; j2 <= jj; ++j2) t3 += ls[j2 * 32 + nl];
        float E = __builtin_amdgcn_exp2f(KC * t3);
        float4 e;
        e.x = W[0 * (LN * NRBF) + jj * NRBF + n] * E;
        e.y = W[1 * (LN * NRBF) + jj * NRBF + n] * E;
        e.z = W[2 * (LN * NRBF) + jj * NRBF + n] * E;
        e.w = 0.f;
        ((float4*)EPI)[((n >> 5) * 8 + jj) * 32 + (n & 31)] = e;
    }
}

// build an A-fragment: elem e even -> x_f^2, odd -> x_f  (f = e>>1 of the quad)
// NOTE: macro parameter must NOT be named x/y/z/w (member-access capture!)
#define CVT(dst, vv)  do {                                         \
        short8 f_;                                                 \
        f_[0] = f2bf((vv).x * (vv).x); f_[1] = f2bf((vv).x);       \
        f_[2] = f2bf((vv).y * (vv).y); f_[3] = f2bf((vv).y);       \
        f_[4] = f2bf((vv).z * (vv).z); f_[5] = f2bf((vv).z);       \
        f_[6] = f2bf((vv).w * (vv).w); f_[7] = f2bf((vv).w);       \
        (dst) = f_; } while (0)

// One wave owns a 32-sample tile. t-OUTER / j-INNER: for each n-tile t
// (32 RBF centers), run the whole 8-layer prefix chain with a SINGLE
// floatx16 accumulator (16 VGPRs live, vs 128 in the j-outer variant that
// spilled). Per (t,j): 2 MFMAs + 16 exps + projection. PKB/EPI per-t
// slices (16+4 KB) double-buffered in LDS via global_load_lds(16B).
__global__ __launch_bounds__(256, 2) void rbf_mfma(
    const float* __restrict__ feats, const short* __restrict__ PKB,
    const float* __restrict__ EPI, const float* __restrict__ bias,
    float* __restrict__ out, int B)
{
    __shared__ short8 pk_s[2][16 * 64];   // 2 x 16 KB
    __shared__ float4 ep_s[2][8 * 32];    // 2 x 4 KB

    int tid  = threadIdx.x;
    int lane = tid & 63;
    int w    = tid >> 6;
    int ntile = (B + 31) >> 5;
    int tile = blockIdx.x * 4 + w;
    bool tvalid = (tile < ntile);
    if (!tvalid) tile = ntile - 1;        // duplicate work, no store
    int b0  = tile * 32;
    int s32 = lane & 31;                  // sample-in-tile for A, n-in-32 for D
    int kh  = lane >> 5;
    int brow = b0 + s32; if (brow >= B) brow = B - 1;
    const float* xrow = feats + (size_t)brow * (LN * FD) + kh * 4;

#define STAGE(buf, tv)                                                          \
    do {                                                                        \
        _Pragma("unroll")                                                       \
        for (int i = 0; i < 4; ++i) {                                           \
            const short* gp = PKB + ((size_t)(tv) * 1024 + (w * 4 + i) * 64 + lane) * 8; \
            __builtin_amdgcn_global_load_lds(                                   \
                (const __attribute__((address_space(1))) void*)gp,              \
                (__attribute__((address_space(3))) void*)&pk_s[buf][(w * 4 + i) * 64], \
                16, 0, 0);                                                      \
        }                                                                       \
        const float* ge = EPI + ((size_t)(tv) * 256 + w * 64 + lane) * 4;       \
        __builtin_amdgcn_global_load_lds(                                       \
            (const __attribute__((address_space(1))) void*)ge,                  \
            (__attribute__((address_space(3))) void*)&ep_s[buf][w * 64],        \
            16, 0, 0);                                                          \
    } while (0)

    // A-fragments for all 8 layers (64 VGPRs), built once
    short8 af0[LN], af1[LN];
#pragma unroll
    for (int j = 0; j < LN; ++j) {
        float4 xa = *(const float4*)(xrow + j * FD);
        float4 xb = *(const float4*)(xrow + j * FD + 8);
        CVT(af0[j], xa);
        CVT(af1[j], xb);
    }

    floatx2 o01[16];
    float   o2[16];
#pragma unroll
    for (int r = 0; r < 16; ++r) { o01[r] = (floatx2){0.f, 0.f}; o2[r] = 0.f; }

    STAGE(0, 0);
    __syncthreads();

#pragma unroll
    for (int t = 0; t < 8; ++t) {
        int cur = t & 1;
        if (t < 7) STAGE(cur ^ 1, t + 1);

        floatx16 acc;
#pragma unroll
        for (int q = 0; q < 16; ++q) acc[q] = 0.f;

#pragma unroll
        for (int j = 0; j < LN; ++j) {
            short8 bf0 = pk_s[cur][(j * 2 + 0) * 64 + lane];
            short8 bf1 = pk_s[cur][(j * 2 + 1) * 64 + lane];
            acc = __builtin_amdgcn_mfma_f32_32x32x16_bf16(af0[j], bf0, acc, 0, 0, 0);
            acc = __builtin_amdgcn_mfma_f32_32x32x16_bf16(af1[j], bf1, acc, 0, 0, 0);

            float4 e = ep_s[cur][j * 32 + s32];
            floatx2 exy = {e.x, e.y};
#pragma unroll
            for (int r = 0; r < 16; ++r) {
                float rv = __builtin_amdgcn_exp2f(acc[r]);
                o01[r] += (floatx2){rv, rv} * exy;
                o2[r]   = fmaf(rv, e.z, o2[r]);
            }
        }
        __syncthreads();
    }
#undef STAGE

    // reduce over the 32 n-lanes (within each lane-half; rows differ by kh)
    float bv = (s32 < OUTD) ? bias[s32] : 0.f;
#pragma unroll
    for (int r = 0; r < 16; ++r) {
        float ax = o01[r].x, ay = o01[r].y, az = o2[r];
        ax += __shfl_xor(ax, 1);  ay += __shfl_xor(ay, 1);  az += __shfl_xor(az, 1);
        ax += __shfl_xor(ax, 2);  ay += __shfl_xor(ay, 2);  az += __shfl_xor(az, 2);
        ax += __shfl_xor(ax, 4);  ay += __shfl_xor(ay, 4);  az += __shfl_xor(az, 4);
        ax += __shfl_xor(ax, 8);  ay += __shfl_xor(ay, 8);  az += __shfl_xor(az, 8);
        ax += __shfl_xor(ax, 16); ay += __shfl_xor(ay, 16); az += __shfl_xor(az, 16);
        if (tvalid && s32 < OUTD) {
            int row = (r & 3) + 8 * (r >> 2) + 4 * kh;   // D-row = sample-in-tile
            int gr  = b0 + row;
            float val = (s32 == 0) ? ax : (s32 == 1) ? ay : az;
            if (gr < B) out[(size_t)gr * OUTD + s32] = val + bv;
        }
    }
}

extern "C" void kernel_launch(void* const* d_in, const int* in_sizes, int n_in,
                              void* d_out, int out_size, void* d_ws, size_t ws_size,
                              hipStream_t stream) {
    // inputs: 0=x (UNUSED by reference), 1=feats, 2=centers, 3=betas, 4=W, 5=b
    const float* feats   = (const float*)d_in[1];
    const float* centers = (const float*)d_in[2];
    const float* betas   = (const float*)d_in[3];
    const float* W       = (const float*)d_in[4];
    const float* bias    = (const float*)d_in[5];
    float* out = (float*)d_out;
    int B = in_sizes[1] / (LN * FD);

    short* PKB = (short*)d_ws;                       // 65536 shorts = 128 KB
    float* EPI = (float*)((char*)d_ws + 65536 * 2);  // 8192 floats = 32 KB

    prep<<<40, 256, 0, stream>>>(centers, betas, W, PKB, EPI);

    int tiles  = (B + 31) / 32;
    int blocks = (tiles + 3) / 4;
    rbf_mfma<<<blocks, 256, 0, stream>>>(feats, PKB, EPI, bias, out, B);
}